// Round 1
// baseline (637.496 us; speedup 1.0000x reference)
//
#include <hip/hip_runtime.h>
#include <hip/hip_bf16.h>
#include <stdint.h>

#define NND 3072
#define DD 300
#define HH 4
#define F2 1200
#define TN 56   // padded LDS row length (elements): 112B stride, 16B-aligned, 2-way-bank-free

typedef __attribute__((ext_vector_type(8))) short short8v;
typedef __attribute__((ext_vector_type(4))) float f32x4;
typedef __hip_bfloat16 bf16;

__device__ inline float ldin(const void* p, size_t i, int isf32) {
    return isf32 ? ((const float*)p)[i]
                 : __bfloat162float(((const bf16*)p)[i]);
}

// ---- dtype sniffer: flags[0]=1 iff float inputs are f32 (not bf16); flags[1]=1 iff adj is int32
__global__ void k_detect(const void* emb, const void* adj, int* flags) {
    if (threadIdx.x == 0 && blockIdx.x == 0) {
        const uint16_t* u = (const uint16_t*)emb;
        int plaus = 0;
        for (int i = 0; i < 128; i++) {
            int e = (u[i] >> 7) & 0xFF;           // bf16 exponent field
            if (e >= 112 && e <= 143) plaus++;    // |v| in ~[2^-15, 2^16]
        }
        flags[0] = (plaus < 100) ? 1 : 0;
        const uint8_t* b = (const uint8_t*)adj;
        int nz = 0;
        for (int i = 0; i < 256; i++) if ((i & 3) != 0 && b[i]) nz++;
        flags[1] = (nz == 0) ? 1 : 0;
    }
}

// ---- T[c][r] = A[r][c], output bf16
__global__ void k_transpose(const void* A, size_t baseOff, bf16* T, int R, int C,
                            const int* flags, int useFlag) {
    __shared__ bf16 t[32][33];
    int isf = useFlag ? flags[0] : 0;
    int rt = blockIdx.y * 32, ct = blockIdx.x * 32;
    int tx = threadIdx.x, ty = threadIdx.y;
    for (int i = 0; i < 4; i++) {
        int r = rt + ty + 8 * i, c = ct + tx;
        if (r < R && c < C)
            t[ty + 8 * i][tx] = __float2bfloat16(ldin(A, baseOff + (size_t)r * C + c, isf));
    }
    __syncthreads();
    for (int i = 0; i < 4; i++) {
        int c = ct + ty + 8 * i, r = rt + tx;
        if (c < C && r < R) T[(size_t)c * R + r] = t[tx][ty + 8 * i];
    }
}

// ---- u1 = W @ a[:C], u2 = W @ a[C:2C]  (one wave per output row)
__global__ void k_uvec(const void* W, const void* a, float* u1, float* u2, int R, int C,
                       long Wb, long ab, long ub, const int* flags) {
    int isf = flags[0];
    int h = blockIdx.y;
    int wid = threadIdx.x >> 6, lane = threadIdx.x & 63;
    int r = blockIdx.x * 4 + wid;
    if (r >= R) return;
    float s1 = 0.f, s2 = 0.f;
    for (int c = lane; c < C; c += 64) {
        float w = ldin(W, (size_t)h * Wb + (size_t)r * C + c, isf);
        s1 += w * ldin(a, (size_t)h * ab + c, isf);
        s2 += w * ldin(a, (size_t)h * ab + C + c, isf);
    }
    for (int o = 32; o; o >>= 1) { s1 += __shfl_down(s1, o); s2 += __shfl_down(s2, o); }
    if (lane == 0) { u1[(size_t)h * ub + r] = s1; u2[(size_t)h * ub + r] = s2; }
}

// ---- o1[i] = X[i,:]·u1, o2[i] = X[i,:]·u2  (one wave per row)
__global__ void k_gemv2(const void* X, const float* u1, const float* u2, float* o1, float* o2,
                        int M, int K, long ub, long ob, const int* flags, int useFlag) {
    int isf = useFlag ? flags[0] : 0;
    int h = blockIdx.y;
    const float* U1 = u1 + (size_t)h * ub;
    const float* U2 = u2 + (size_t)h * ub;
    int wid = threadIdx.x >> 6, lane = threadIdx.x & 63;
    int row = blockIdx.x * 4 + wid;
    if (row >= M) return;
    float s1 = 0.f, s2 = 0.f;
    for (int k = lane; k < K; k += 64) {
        float x = ldin(X, (size_t)row * K + k, isf);
        s1 += x * U1[k]; s2 += x * U2[k];
    }
    for (int o = 32; o; o >>= 1) { s1 += __shfl_down(s1, o); s2 += __shfl_down(s2, o); }
    if (lane == 0) { o1[(size_t)h * ob + row] = s1; o2[(size_t)h * ob + row] = s2; }
}

// ---- per-row two-sided masked softmax (unnormalized); stores reciprocal sums
__global__ __launch_bounds__(256) void k_score(const float* Wh1, const float* Wh2, const void* adj,
                                               bf16* Pp, bf16* Pn, float* Sp, float* Sn,
                                               const int* flags) {
    int i = blockIdx.x;
    int tidx = threadIdx.x, wid = tidx >> 6, lane = tidx & 63;
    int adjInt = flags[1];
    const uint8_t* a8 = (const uint8_t*)adj;
    const int* a32 = (const int*)adj;
    float w1 = Wh1[i];
    float mp = -1e30f, mn = -1e30f;
    for (int j = tidx; j < NND; j += 256) {
        size_t idx = (size_t)i * NND + j;
        int on = adjInt ? a32[idx] : (int)a8[idx];
        if (on) {
            float z = w1 + Wh2[j];
            float e = z > 0.f ? z : 0.3f * z;   // leaky_relu(0.3)
            mp = fmaxf(mp, e); mn = fmaxf(mn, -e);
        }
    }
    __shared__ float r1[4], r2[4];
    for (int o = 32; o; o >>= 1) { mp = fmaxf(mp, __shfl_down(mp, o)); mn = fmaxf(mn, __shfl_down(mn, o)); }
    if (lane == 0) { r1[wid] = mp; r2[wid] = mn; }
    __syncthreads();
    mp = fmaxf(fmaxf(r1[0], r1[1]), fmaxf(r1[2], r1[3]));
    mn = fmaxf(fmaxf(r2[0], r2[1]), fmaxf(r2[2], r2[3]));
    __syncthreads();
    float sp = 0.f, sn = 0.f;
    for (int j = tidx; j < NND; j += 256) {
        size_t idx = (size_t)i * NND + j;
        int on = adjInt ? a32[idx] : (int)a8[idx];
        float p = 0.f, q = 0.f;
        if (on) {
            float z = w1 + Wh2[j];
            float e = z > 0.f ? z : 0.3f * z;
            p = __expf(e - mp);
            q = __expf(-e - mn);
        }
        Pp[idx] = __float2bfloat16(p);
        Pn[idx] = __float2bfloat16(q);
        sp += p; sn += q;
    }
    for (int o = 32; o; o >>= 1) { sp += __shfl_down(sp, o); sn += __shfl_down(sn, o); }
    if (lane == 0) { r1[wid] = sp; r2[wid] = sn; }
    __syncthreads();
    if (tidx == 0) {
        sp = r1[0] + r1[1] + r1[2] + r1[3];
        sn = r2[0] + r2[1] + r2[2] + r2[3];
        Sp[i] = 1.0f / sp;
        Sn[i] = -1.0f / sn;   // fold neg_att's minus sign here
    }
}

// ---- CC[:,0:F] = diag(Sp)·(Pp@X), CC[:,F:2F] = diag(Sn)·(Pn@X); X given transposed [F][NND]
__global__ __launch_bounds__(256) void k_attgemm(const bf16* __restrict__ Pp, const bf16* __restrict__ Pn,
                                                 const bf16* __restrict__ Xt,
                                                 const float* __restrict__ Sp, const float* __restrict__ Sn,
                                                 bf16* __restrict__ CC, int F, int ccStride) {
    __shared__ __align__(16) bf16 Alds[2][64 * TN];
    __shared__ __align__(16) bf16 Blds[64 * TN];
    int tid = threadIdx.x, lane = tid & 63, w = tid >> 6, wr = w >> 1, wc = w & 1;
    int m0 = blockIdx.y * 64, n0 = blockIdx.x * 64;
    int sm = tid >> 2, sk = (tid & 3) * 8;
    f32x4 cp[2][2] = {};
    f32x4 cn[2][2] = {};
    for (int k0 = 0; k0 < NND; k0 += 32) {
        uint4 va = *(const uint4*)(Pp + (size_t)(m0 + sm) * NND + k0 + sk);
        uint4 vb = *(const uint4*)(Pn + (size_t)(m0 + sm) * NND + k0 + sk);
        uint4 vx = make_uint4(0, 0, 0, 0);
        if (n0 + sm < F) vx = *(const uint4*)(Xt + (size_t)(n0 + sm) * NND + k0 + sk);
        __syncthreads();
        *(uint4*)&Alds[0][sm * TN + sk] = va;
        *(uint4*)&Alds[1][sm * TN + sk] = vb;
        *(uint4*)&Blds[sm * TN + sk] = vx;
        __syncthreads();
        int ar = wr * 32 + (lane & 15), koff = (lane >> 4) * 8;
        int br = wc * 32 + (lane & 15);
        short8v a0 = *(const short8v*)&Alds[0][ar * TN + koff];
        short8v a1 = *(const short8v*)&Alds[0][(ar + 16) * TN + koff];
        short8v e0 = *(const short8v*)&Alds[1][ar * TN + koff];
        short8v e1 = *(const short8v*)&Alds[1][(ar + 16) * TN + koff];
        short8v b0 = *(const short8v*)&Blds[br * TN + koff];
        short8v b1 = *(const short8v*)&Blds[(br + 16) * TN + koff];
        cp[0][0] = __builtin_amdgcn_mfma_f32_16x16x32_bf16(a0, b0, cp[0][0], 0, 0, 0);
        cp[0][1] = __builtin_amdgcn_mfma_f32_16x16x32_bf16(a0, b1, cp[0][1], 0, 0, 0);
        cp[1][0] = __builtin_amdgcn_mfma_f32_16x16x32_bf16(a1, b0, cp[1][0], 0, 0, 0);
        cp[1][1] = __builtin_amdgcn_mfma_f32_16x16x32_bf16(a1, b1, cp[1][1], 0, 0, 0);
        cn[0][0] = __builtin_amdgcn_mfma_f32_16x16x32_bf16(e0, b0, cn[0][0], 0, 0, 0);
        cn[0][1] = __builtin_amdgcn_mfma_f32_16x16x32_bf16(e0, b1, cn[0][1], 0, 0, 0);
        cn[1][0] = __builtin_amdgcn_mfma_f32_16x16x32_bf16(e1, b0, cn[1][0], 0, 0, 0);
        cn[1][1] = __builtin_amdgcn_mfma_f32_16x16x32_bf16(e1, b1, cn[1][1], 0, 0, 0);
    }
    for (int ni = 0; ni < 2; ni++) {
        int col = n0 + wc * 32 + ni * 16 + (lane & 15);
        if (col >= F) continue;
        for (int mi = 0; mi < 2; mi++) {
            int rbase = m0 + wr * 32 + mi * 16 + (lane >> 4) * 4;
            for (int r = 0; r < 4; r++) {
                int row = rbase + r;
                CC[(size_t)row * ccStride + col]     = __float2bfloat16(cp[mi][ni][r] * Sp[row]);
                CC[(size_t)row * ccStride + F + col] = __float2bfloat16(cn[mi][ni][r] * Sn[row]);
            }
        }
    }
}

// ---- Out[:,off:off+N] = epi(A @ Bt^T); A [3072,K] bf16, Bt [Ncols][K] bf16; mode 0=ELU, 1=sigmoid
__global__ __launch_bounds__(256) void k_ccgemm(const bf16* __restrict__ A, const bf16* __restrict__ Bt,
                                                bf16* __restrict__ Out, int K, int Ncols,
                                                int outStride, int outColOff, int mode) {
    __shared__ __align__(16) bf16 Alds[64 * TN];
    __shared__ __align__(16) bf16 Blds[64 * TN];
    int tid = threadIdx.x, lane = tid & 63, w = tid >> 6, wr = w >> 1, wc = w & 1;
    int m0 = blockIdx.y * 64, n0 = blockIdx.x * 64;
    int sm = tid >> 2, sk = (tid & 3) * 8;
    f32x4 acc[2][2] = {};
    for (int k0 = 0; k0 < K; k0 += 32) {
        uint4 va = make_uint4(0, 0, 0, 0), vx = make_uint4(0, 0, 0, 0);
        if (k0 + sk < K) va = *(const uint4*)(A + (size_t)(m0 + sm) * K + k0 + sk);
        if (n0 + sm < Ncols && k0 + sk < K) vx = *(const uint4*)(Bt + (size_t)(n0 + sm) * K + k0 + sk);
        __syncthreads();
        *(uint4*)&Alds[sm * TN + sk] = va;
        *(uint4*)&Blds[sm * TN + sk] = vx;
        __syncthreads();
        int ar = wr * 32 + (lane & 15), koff = (lane >> 4) * 8;
        int br = wc * 32 + (lane & 15);
        short8v a0 = *(const short8v*)&Alds[ar * TN + koff];
        short8v a1 = *(const short8v*)&Alds[(ar + 16) * TN + koff];
        short8v b0 = *(const short8v*)&Blds[br * TN + koff];
        short8v b1 = *(const short8v*)&Blds[(br + 16) * TN + koff];
        acc[0][0] = __builtin_amdgcn_mfma_f32_16x16x32_bf16(a0, b0, acc[0][0], 0, 0, 0);
        acc[0][1] = __builtin_amdgcn_mfma_f32_16x16x32_bf16(a0, b1, acc[0][1], 0, 0, 0);
        acc[1][0] = __builtin_amdgcn_mfma_f32_16x16x32_bf16(a1, b0, acc[1][0], 0, 0, 0);
        acc[1][1] = __builtin_amdgcn_mfma_f32_16x16x32_bf16(a1, b1, acc[1][1], 0, 0, 0);
    }
    for (int ni = 0; ni < 2; ni++) {
        int col = n0 + wc * 32 + ni * 16 + (lane & 15);
        if (col >= Ncols) continue;
        for (int mi = 0; mi < 2; mi++) {
            int rbase = m0 + wr * 32 + mi * 16 + (lane >> 4) * 4;
            for (int r = 0; r < 4; r++) {
                float v = acc[mi][ni][r];
                if (mode == 0) v = v > 0.f ? v : (__expf(v) - 1.0f);          // ELU
                else           v = 1.0f / (1.0f + __expf(-v));                 // sigmoid
                Out[(size_t)(rbase + r) * outStride + outColOff + col] = __float2bfloat16(v);
            }
        }
    }
}

__global__ void k_gather(const bf16* full, const int* ids, void* out, const int* flags) {
    int idx = blockIdx.x * 256 + threadIdx.x;
    if (idx >= 64 * DD) return;
    int t = idx / DD, d = idx - t * DD;
    float v = __bfloat162float(full[(size_t)ids[t] * DD + d]);
    if (flags[0]) ((float*)out)[idx] = v;
    else ((bf16*)out)[idx] = __float2bfloat16(v);
}

extern "C" void kernel_launch(void* const* d_in, const int* in_sizes, int n_in,
                              void* d_out, int out_size, void* d_ws, size_t ws_size,
                              hipStream_t stream) {
    const void* emb = d_in[0];
    const void* Whd = d_in[1];
    const void* ahd = d_in[2];
    const void* wth = d_in[3];
    const void* Wo  = d_in[4];
    const void* ao  = d_in[5];
    const void* wto = d_in[6];
    const void* adj = d_in[7];
    const int* tid  = (const int*)d_in[8];

    char* p = (char*)d_ws;
    auto alloc = [&](size_t bytes) { void* r = (void*)p; p += ((bytes + 255) / 256) * 256; return r; };
    int*   flags = (int*)  alloc(256);
    bf16*  Pp    = (bf16*) alloc((size_t)NND * NND * 2);
    bf16*  Pn    = (bf16*) alloc((size_t)NND * NND * 2);
    float* Sp    = (float*)alloc((size_t)NND * 4);
    float* Sn    = (float*)alloc((size_t)NND * 4);
    float* uh1   = (float*)alloc((size_t)HH * DD * 4);
    float* uh2   = (float*)alloc((size_t)HH * DD * 4);
    float* uo1   = (float*)alloc((size_t)F2 * 4);
    float* uo2   = (float*)alloc((size_t)F2 * 4);
    float* Wh1h  = (float*)alloc((size_t)HH * NND * 4);
    float* Wh2h  = (float*)alloc((size_t)HH * NND * 4);
    float* Wh1o  = (float*)alloc((size_t)NND * 4);
    float* Wh2o  = (float*)alloc((size_t)NND * 4);
    bf16*  X1t   = (bf16*) alloc((size_t)DD * NND * 2);
    bf16*  x2    = (bf16*) alloc((size_t)NND * F2 * 2);
    bf16*  X2t   = (bf16*) alloc((size_t)F2 * NND * 2);
    bf16*  cc    = (bf16*) alloc((size_t)NND * 2 * F2 * 2);
    bf16*  wtT   = (bf16*) alloc((size_t)DD * 2 * F2 * 2);
    bf16*  ofull = (bf16*) alloc((size_t)NND * DD * 2);

    dim3 tb(32, 8);
    k_detect<<<1, 64, 0, stream>>>(emb, adj, flags);
    // X1t = emb^T  [300][3072]
    k_transpose<<<dim3((DD + 31) / 32, (NND + 31) / 32), tb, 0, stream>>>(emb, 0, X1t, NND, DD, flags, 1);
    // per-head u vectors: u1 = W@a[:D], u2 = W@a[D:]
    k_uvec<<<dim3((DD + 3) / 4, HH), 256, 0, stream>>>(Whd, ahd, uh1, uh2, DD, DD,
                                                       (long)DD * DD, (long)2 * DD, DD, flags);
    // Wh1/Wh2 for all heads: x @ u
    k_gemv2<<<dim3(NND / 4, HH), 256, 0, stream>>>(emb, uh1, uh2, Wh1h, Wh2h, NND, DD, DD, NND, flags, 1);

    for (int l = 0; l < HH; l++) {
        k_score<<<NND, 256, 0, stream>>>(Wh1h + (size_t)l * NND, Wh2h + (size_t)l * NND, adj,
                                         Pp, Pn, Sp, Sn, flags);
        k_attgemm<<<dim3((DD + 63) / 64, NND / 64), 256, 0, stream>>>(Pp, Pn, X1t, Sp, Sn, cc, DD, 2 * DD);
        k_transpose<<<dim3((DD + 31) / 32, (2 * DD + 31) / 32), tb, 0, stream>>>(
            wth, (size_t)l * 2 * DD * DD, wtT, 2 * DD, DD, flags, 1);
        k_ccgemm<<<dim3((DD + 63) / 64, NND / 64), 256, 0, stream>>>(cc, wtT, x2, 2 * DD, DD, F2, l * DD, 0);
    }

    // output layer
    k_transpose<<<dim3((F2 + 31) / 32, (NND + 31) / 32), tb, 0, stream>>>(x2, 0, X2t, NND, F2, flags, 0);
    k_uvec<<<dim3((F2 + 3) / 4, 1), 256, 0, stream>>>(Wo, ao, uo1, uo2, F2, DD, 0, 0, 0, flags);
    k_gemv2<<<dim3(NND / 4, 1), 256, 0, stream>>>(x2, uo1, uo2, Wh1o, Wh2o, NND, F2, 0, 0, flags, 0);
    k_score<<<NND, 256, 0, stream>>>(Wh1o, Wh2o, adj, Pp, Pn, Sp, Sn, flags);
    k_attgemm<<<dim3((F2 + 63) / 64, NND / 64), 256, 0, stream>>>(Pp, Pn, X2t, Sp, Sn, cc, F2, 2 * F2);
    k_transpose<<<dim3((DD + 31) / 32, (2 * F2 + 31) / 32), tb, 0, stream>>>(wto, 0, wtT, 2 * F2, DD, flags, 1);
    k_ccgemm<<<dim3((DD + 63) / 64, NND / 64), 256, 0, stream>>>(cc, wtT, ofull, 2 * F2, DD, DD, 0, 1);
    k_gather<<<(64 * DD + 255) / 256, 256, 0, stream>>>(ofull, tid, d_out, flags);
}

// Round 3
// 600.294 us; speedup vs baseline: 1.0620x; 1.0620x over previous
//
#include <hip/hip_runtime.h>
#include <hip/hip_bf16.h>
#include <stdint.h>

#define NND 3072
#define DD 300
#define HH 4
#define F2 1200
#define TN 56    // ccgemm LDS pad
#define TNA 40   // fused-attgemm A-tile pad (k32 + 8): 80B stride, even bank-quad spread

typedef __attribute__((ext_vector_type(8))) short short8v;
typedef __attribute__((ext_vector_type(4))) float f32x4;
typedef __hip_bfloat16 bf16;

__device__ inline float ldin(const void* p, size_t i, int isf32) {
    return isf32 ? ((const float*)p)[i]
                 : __bfloat162float(((const bf16*)p)[i]);
}

__device__ inline ushort f2bf(float x) {
    bf16 t = __float2bfloat16(x);
    return *reinterpret_cast<ushort*>(&t);
}

// ---- dtype sniffer: flags[0]=1 iff float inputs are f32; flags[1]=1 iff adj is int32
__global__ void k_detect(const void* emb, const void* adj, int* flags) {
    if (threadIdx.x == 0 && blockIdx.x == 0) {
        const uint16_t* u = (const uint16_t*)emb;
        int plaus = 0;
        for (int i = 0; i < 128; i++) {
            int e = (u[i] >> 7) & 0xFF;
            if (e >= 112 && e <= 143) plaus++;
        }
        flags[0] = (plaus < 100) ? 1 : 0;
        const uint8_t* b = (const uint8_t*)adj;
        int nz = 0;
        for (int i = 0; i < 256; i++) if ((i & 3) != 0 && b[i]) nz++;
        flags[1] = (nz == 0) ? 1 : 0;
    }
}

// ---- T[c][r] = A[r][c], output bf16.  grid = ((C+31)/32, (R+31)/32)
__global__ void k_transpose(const void* A, size_t baseOff, bf16* T, int R, int C,
                            const int* flags, int useFlag) {
    __shared__ bf16 t[32][33];
    int isf = useFlag ? flags[0] : 0;
    int rt = blockIdx.y * 32, ct = blockIdx.x * 32;
    int tx = threadIdx.x, ty = threadIdx.y;
    for (int i = 0; i < 4; i++) {
        int r = rt + ty + 8 * i, c = ct + tx;
        if (r < R && c < C)
            t[ty + 8 * i][tx] = __float2bfloat16(ldin(A, baseOff + (size_t)r * C + c, isf));
    }
    __syncthreads();
    for (int i = 0; i < 4; i++) {
        int c = ct + ty + 8 * i, r = rt + tx;
        if (c < C && r < R) T[(size_t)c * R + r] = t[tx][ty + 8 * i];
    }
}

// ---- u1 = W @ a[:C], u2 = W @ a[C:2C]
__global__ void k_uvec(const void* W, const void* a, float* u1, float* u2, int R, int C,
                       long Wb, long ab, long ub, const int* flags) {
    int isf = flags[0];
    int h = blockIdx.y;
    int wid = threadIdx.x >> 6, lane = threadIdx.x & 63;
    int r = blockIdx.x * 4 + wid;
    if (r >= R) return;
    float s1 = 0.f, s2 = 0.f;
    for (int c = lane; c < C; c += 64) {
        float w = ldin(W, (size_t)h * Wb + (size_t)r * C + c, isf);
        s1 += w * ldin(a, (size_t)h * ab + c, isf);
        s2 += w * ldin(a, (size_t)h * ab + C + c, isf);
    }
    for (int o = 32; o; o >>= 1) { s1 += __shfl_down(s1, o); s2 += __shfl_down(s2, o); }
    if (lane == 0) { u1[(size_t)h * ub + r] = s1; u2[(size_t)h * ub + r] = s2; }
}

// ---- o1[i] = X[i,:]·u1, o2[i] = X[i,:]·u2
__global__ void k_gemv2(const void* X, const float* u1, const float* u2, float* o1, float* o2,
                        int M, int K, long ub, long ob, const int* flags, int useFlag) {
    int isf = useFlag ? flags[0] : 0;
    int h = blockIdx.y;
    const float* U1 = u1 + (size_t)h * ub;
    const float* U2 = u2 + (size_t)h * ub;
    int wid = threadIdx.x >> 6, lane = threadIdx.x & 63;
    int row = blockIdx.x * 4 + wid;
    if (row >= M) return;
    float s1 = 0.f, s2 = 0.f;
    for (int k = lane; k < K; k += 64) {
        float x = ldin(X, (size_t)row * K + k, isf);
        s1 += x * U1[k]; s2 += x * U2[k];
    }
    for (int o = 32; o; o >>= 1) { s1 += __shfl_down(s1, o); s2 += __shfl_down(s2, o); }
    if (lane == 0) { o1[(size_t)h * ob + row] = s1; o2[(size_t)h * ob + row] = s2; }
}

// ---- per-row two-sided masked softmax stats: row max (mp,mn) and reciprocal sums
__global__ __launch_bounds__(256) void k_stats(const float* __restrict__ Wh1A,
                                               const float* __restrict__ Wh2A, long hs,
                                               const void* __restrict__ adj, const int* __restrict__ flags,
                                               float* __restrict__ mpA, float* __restrict__ mnA,
                                               float* __restrict__ rspA, float* __restrict__ rsnA) {
    int h = blockIdx.y;
    const float* Wh1 = Wh1A + (size_t)h * hs;
    const float* Wh2 = Wh2A + (size_t)h * hs;
    int i = blockIdx.x;
    int tidx = threadIdx.x, wid = tidx >> 6, lane = tidx & 63;
    int adjInt = flags[1];
    const uint8_t* a8 = (const uint8_t*)adj;
    const int* a32 = (const int*)adj;
    float w1 = Wh1[i];
    float mp = -1e30f, mn = -1e30f;
    for (int j = tidx; j < NND; j += 256) {
        size_t idx = (size_t)i * NND + j;
        int on = adjInt ? a32[idx] : (int)a8[idx];
        if (on) {
            float z = w1 + Wh2[j];
            float e = fmaxf(z, 0.3f * z);
            mp = fmaxf(mp, e); mn = fmaxf(mn, -e);
        }
    }
    __shared__ float r1[4], r2[4];
    for (int o = 32; o; o >>= 1) { mp = fmaxf(mp, __shfl_down(mp, o)); mn = fmaxf(mn, __shfl_down(mn, o)); }
    if (lane == 0) { r1[wid] = mp; r2[wid] = mn; }
    __syncthreads();
    mp = fmaxf(fmaxf(r1[0], r1[1]), fmaxf(r1[2], r1[3]));
    mn = fmaxf(fmaxf(r2[0], r2[1]), fmaxf(r2[2], r2[3]));
    __syncthreads();
    float sp = 0.f, sn = 0.f;
    for (int j = tidx; j < NND; j += 256) {
        size_t idx = (size_t)i * NND + j;
        int on = adjInt ? a32[idx] : (int)a8[idx];
        if (on) {
            float z = w1 + Wh2[j];
            float e = fmaxf(z, 0.3f * z);
            sp += __expf(e - mp);
            sn += __expf(-e - mn);
        }
    }
    for (int o = 32; o; o >>= 1) { sp += __shfl_down(sp, o); sn += __shfl_down(sn, o); }
    if (lane == 0) { r1[wid] = sp; r2[wid] = sn; }
    __syncthreads();
    if (tidx == 0) {
        sp = r1[0] + r1[1] + r1[2] + r1[3];
        sn = r2[0] + r2[1] + r2[2] + r2[3];
        size_t o = (size_t)h * NND + i;
        mpA[o] = mp; mnA[o] = mn;
        rspA[o] = 1.0f / sp;
        rsnA[o] = -1.0f / sn;   // fold neg_att's minus sign
    }
}

// ---- fused attention GEMM: P computed on the fly, never materialized.
// CC[:,0:F] = diag(rsp)·(Ppos@Xt^T), CC[:,F:2F] = diag(rsn)·(Pneg@Xt^T)
// Xt: [nPad][3072] bf16 (rows >= gridDim.x*160, zero-padded). blockIdx.z = head.
__global__ __launch_bounds__(256) void k_fattgemm(
    const float* __restrict__ Wh1A, const float* __restrict__ Wh2A,
    const float* __restrict__ mpA, const float* __restrict__ mnA,
    const float* __restrict__ rspA, const float* __restrict__ rsnA, long hs,
    const void* __restrict__ adj, const int* __restrict__ flags,
    const bf16* __restrict__ Xt, bf16* __restrict__ CC,
    long ccHeadStride, int ccStride, int F) {
    __shared__ __align__(16) bf16 Ap[64 * TNA];
    __shared__ __align__(16) bf16 An[64 * TNA];
    int h = blockIdx.z;
    const float* Wh1 = Wh1A + (size_t)h * hs;
    const float* Wh2 = Wh2A + (size_t)h * hs;
    const float* mp_ = mpA + (size_t)h * hs;
    const float* mn_ = mnA + (size_t)h * hs;
    const float* rsp = rspA + (size_t)h * hs;
    const float* rsn = rsnA + (size_t)h * hs;
    bf16* C = CC + (size_t)h * ccHeadStride;
    int m0 = blockIdx.y * 64, n0 = blockIdx.x * 160;
    int tid = threadIdx.x, lane = tid & 63, w = tid >> 6, wr = w >> 1, wn = w & 1;
    int sm = tid >> 2, sk = (tid & 3) * 8;
    int srow = m0 + sm;
    float w1 = Wh1[srow], mpv = mp_[srow], mnv = mn_[srow];
    int adjInt = flags[1];
    const uint8_t* arow8 = (const uint8_t*)adj + (size_t)srow * NND;
    const int* arow32 = (const int*)adj + (size_t)srow * NND;
    f32x4 cp[2][5] = {};
    f32x4 cn[2][5] = {};
    int ar = wr * 32 + (lane & 15);
    int ko = (lane >> 4) * 8;
    const bf16* Bbase = Xt + (size_t)(n0 + wn * 80 + (lane & 15)) * NND + ko;

    for (int k0 = 0; k0 < NND; k0 += 32) {
        // build 8-neighbor mask
        unsigned msk = 0;
        if (!adjInt) {
            uint2 ab = *(const uint2*)(arow8 + k0 + sk);
            #pragma unroll
            for (int jj = 0; jj < 4; jj++) {
                if ((ab.x >> (8 * jj)) & 0xffu) msk |= 1u << jj;
                if ((ab.y >> (8 * jj)) & 0xffu) msk |= 1u << (4 + jj);
            }
        } else {
            int4 u = *(const int4*)(arow32 + k0 + sk);
            int4 v = *(const int4*)(arow32 + k0 + sk + 4);
            if (u.x) msk |= 1;  if (u.y) msk |= 2;   if (u.z) msk |= 4;   if (u.w) msk |= 8;
            if (v.x) msk |= 16; if (v.y) msk |= 32;  if (v.z) msk |= 64;  if (v.w) msk |= 128;
        }
        float4 wa = *(const float4*)(Wh2 + k0 + sk);
        float4 wb = *(const float4*)(Wh2 + k0 + sk + 4);
        float zs[8] = {wa.x, wa.y, wa.z, wa.w, wb.x, wb.y, wb.z, wb.w};
        ushort pu[8], qu[8];
        #pragma unroll
        for (int jj = 0; jj < 8; jj++) {
            float z = w1 + zs[jj];
            float e = fmaxf(z, 0.3f * z);            // leaky_relu(0.3)
            float pe = __expf(e - mpv);
            float qe = __expf(-e - mnv);
            bool on = (msk >> jj) & 1u;
            pu[jj] = f2bf(on ? pe : 0.0f);
            qu[jj] = f2bf(on ? qe : 0.0f);
        }
        __syncthreads();
        *(short8v*)&Ap[sm * TNA + sk] = *(const short8v*)pu;
        *(short8v*)&An[sm * TNA + sk] = *(const short8v*)qu;
        __syncthreads();
        short8v a0 = *(const short8v*)&Ap[ar * TNA + ko];
        short8v a1 = *(const short8v*)&Ap[(ar + 16) * TNA + ko];
        short8v e0 = *(const short8v*)&An[ar * TNA + ko];
        short8v e1 = *(const short8v*)&An[(ar + 16) * TNA + ko];
        #pragma unroll
        for (int f = 0; f < 5; f++) {
            short8v b = *(const short8v*)(Bbase + (size_t)f * 16 * NND + k0);
            cp[0][f] = __builtin_amdgcn_mfma_f32_16x16x32_bf16(a0, b, cp[0][f], 0, 0, 0);
            cp[1][f] = __builtin_amdgcn_mfma_f32_16x16x32_bf16(a1, b, cp[1][f], 0, 0, 0);
            cn[0][f] = __builtin_amdgcn_mfma_f32_16x16x32_bf16(e0, b, cn[0][f], 0, 0, 0);
            cn[1][f] = __builtin_amdgcn_mfma_f32_16x16x32_bf16(e1, b, cn[1][f], 0, 0, 0);
        }
    }
    #pragma unroll
    for (int mi = 0; mi < 2; mi++) {
        int rbase = m0 + wr * 32 + mi * 16 + (lane >> 4) * 4;
        #pragma unroll
        for (int r = 0; r < 4; r++) {
            int row = rbase + r;
            float sp_ = rsp[row], sn_ = rsn[row];
            #pragma unroll
            for (int f = 0; f < 5; f++) {
                int col = n0 + wn * 80 + f * 16 + (lane & 15);
                if (col < F) {
                    C[(size_t)row * ccStride + col]     = __float2bfloat16(cp[mi][f][r] * sp_);
                    C[(size_t)row * ccStride + F + col] = __float2bfloat16(cn[mi][f][r] * sn_);
                }
            }
        }
    }
}

// ---- Out[:,off:off+N] = epi(A @ Bt^T); head-batched via blockIdx.z
__global__ __launch_bounds__(256) void k_ccgemm(const bf16* __restrict__ A0, const bf16* __restrict__ Bt0,
                                                bf16* __restrict__ Out, int K, int Ncols,
                                                int outStride, int outColOff0, int mode,
                                                long aHeadStride, long btHeadStride, int outColStep) {
    __shared__ __align__(16) bf16 Alds[64 * TN];
    __shared__ __align__(16) bf16 Blds[64 * TN];
    int h = blockIdx.z;
    const bf16* A = A0 + (size_t)h * aHeadStride;
    const bf16* Bt = Bt0 + (size_t)h * btHeadStride;
    int outColOff = outColOff0 + h * outColStep;
    int tid = threadIdx.x, lane = tid & 63, w = tid >> 6, wr = w >> 1, wc = w & 1;
    int m0 = blockIdx.y * 64, n0 = blockIdx.x * 64;
    int sm = tid >> 2, sk = (tid & 3) * 8;
    f32x4 acc[2][2] = {};
    for (int k0 = 0; k0 < K; k0 += 32) {
        uint4 va = make_uint4(0, 0, 0, 0), vx = make_uint4(0, 0, 0, 0);
        if (k0 + sk < K) va = *(const uint4*)(A + (size_t)(m0 + sm) * K + k0 + sk);
        if (n0 + sm < Ncols && k0 + sk < K) vx = *(const uint4*)(Bt + (size_t)(n0 + sm) * K + k0 + sk);
        __syncthreads();
        *(uint4*)&Alds[sm * TN + sk] = va;
        *(uint4*)&Blds[sm * TN + sk] = vx;
        __syncthreads();
        int ar = wr * 32 + (lane & 15), koff = (lane >> 4) * 8;
        int br = wc * 32 + (lane & 15);
        short8v a0 = *(const short8v*)&Alds[ar * TN + koff];
        short8v a1 = *(const short8v*)&Alds[(ar + 16) * TN + koff];
        short8v b0 = *(const short8v*)&Blds[br * TN + koff];
        short8v b1 = *(const short8v*)&Blds[(br + 16) * TN + koff];
        acc[0][0] = __builtin_amdgcn_mfma_f32_16x16x32_bf16(a0, b0, acc[0][0], 0, 0, 0);
        acc[0][1] = __builtin_amdgcn_mfma_f32_16x16x32_bf16(a0, b1, acc[0][1], 0, 0, 0);
        acc[1][0] = __builtin_amdgcn_mfma_f32_16x16x32_bf16(a1, b0, acc[1][0], 0, 0, 0);
        acc[1][1] = __builtin_amdgcn_mfma_f32_16x16x32_bf16(a1, b1, acc[1][1], 0, 0, 0);
    }
    for (int ni = 0; ni < 2; ni++) {
        int col = n0 + wc * 32 + ni * 16 + (lane & 15);
        if (col >= Ncols) continue;
        for (int mi = 0; mi < 2; mi++) {
            int rbase = m0 + wr * 32 + mi * 16 + (lane >> 4) * 4;
            for (int r = 0; r < 4; r++) {
                float v = acc[mi][ni][r];
                if (mode == 0) v = v > 0.f ? v : (__expf(v) - 1.0f);
                else           v = 1.0f / (1.0f + __expf(-v));
                Out[(size_t)(rbase + r) * outStride + outColOff + col] = __float2bfloat16(v);
            }
        }
    }
}

__global__ void k_gather(const bf16* full, const int* ids, void* out, const int* flags) {
    int idx = blockIdx.x * 256 + threadIdx.x;
    if (idx >= 64 * DD) return;
    int t = idx / DD, d = idx - t * DD;
    float v = __bfloat162float(full[(size_t)ids[t] * DD + d]);
    if (flags[0]) ((float*)out)[idx] = v;
    else ((bf16*)out)[idx] = __float2bfloat16(v);
}

extern "C" void kernel_launch(void* const* d_in, const int* in_sizes, int n_in,
                              void* d_out, int out_size, void* d_ws, size_t ws_size,
                              hipStream_t stream) {
    const void* emb = d_in[0];
    const void* Whd = d_in[1];
    const void* ahd = d_in[2];
    const void* wth = d_in[3];
    const void* Wo  = d_in[4];
    const void* ao  = d_in[5];
    const void* wto = d_in[6];
    const void* adj = d_in[7];
    const int* tid  = (const int*)d_in[8];

    char* p = (char*)d_ws;
    auto alloc = [&](size_t bytes) { void* r = (void*)p; p += ((bytes + 255) / 256) * 256; return r; };
    int*   flags = (int*)  alloc(256);
    bf16*  X1t   = (bf16*) alloc((size_t)320 * NND * 2);     // emb^T, padded to 320 rows
    bf16*  X2t   = (bf16*) alloc((size_t)1280 * NND * 2);    // x2^T, padded to 1280 rows
    bf16*  x2    = (bf16*) alloc((size_t)NND * F2 * 2);
    bf16*  cc4   = (bf16*) alloc((size_t)HH * NND * 2 * DD * 2);
    bf16*  ccO   = (bf16*) alloc((size_t)NND * 2 * F2 * 2);
    bf16*  wtT4  = (bf16*) alloc((size_t)HH * DD * 2 * DD * 2);
    bf16*  wtTo  = (bf16*) alloc((size_t)DD * 2 * F2 * 2);
    bf16*  ofull = (bf16*) alloc((size_t)NND * DD * 2);
    float* uh1   = (float*)alloc((size_t)HH * DD * 4);
    float* uh2   = (float*)alloc((size_t)HH * DD * 4);
    float* uo1   = (float*)alloc((size_t)F2 * 4);
    float* uo2   = (float*)alloc((size_t)F2 * 4);
    float* Wh1h  = (float*)alloc((size_t)HH * NND * 4);
    float* Wh2h  = (float*)alloc((size_t)HH * NND * 4);
    float* Wh1o  = (float*)alloc((size_t)NND * 4);
    float* Wh2o  = (float*)alloc((size_t)NND * 4);
    float* mph   = (float*)alloc((size_t)HH * NND * 4);
    float* mnh   = (float*)alloc((size_t)HH * NND * 4);
    float* rsph  = (float*)alloc((size_t)HH * NND * 4);
    float* rsnh  = (float*)alloc((size_t)HH * NND * 4);
    float* mpo   = (float*)alloc((size_t)NND * 4);
    float* mno   = (float*)alloc((size_t)NND * 4);
    float* rspo  = (float*)alloc((size_t)NND * 4);
    float* rsno  = (float*)alloc((size_t)NND * 4);

    dim3 tb(32, 8);
    k_detect<<<1, 64, 0, stream>>>(emb, adj, flags);
    hipMemsetAsync(X1t, 0, (size_t)320 * NND * 2, stream);
    hipMemsetAsync(X2t, 0, (size_t)1280 * NND * 2, stream);
    // X1t = emb^T: A is [R=3072][C=300] -> grid ((C+31)/32, (R+31)/32)
    k_transpose<<<dim3((DD + 31) / 32, (NND + 31) / 32), tb, 0, stream>>>(emb, 0, X1t, NND, DD, flags, 1);
    k_uvec<<<dim3((DD + 3) / 4, HH), 256, 0, stream>>>(Whd, ahd, uh1, uh2, DD, DD,
                                                       (long)DD * DD, (long)2 * DD, DD, flags);
    k_gemv2<<<dim3(NND / 4, HH), 256, 0, stream>>>(emb, uh1, uh2, Wh1h, Wh2h, NND, DD, DD, NND, flags, 1);
    k_stats<<<dim3(NND, HH), 256, 0, stream>>>(Wh1h, Wh2h, NND, adj, flags, mph, mnh, rsph, rsnh);
    // all 4 heads' fused attention GEMM in one dispatch
    k_fattgemm<<<dim3(2, 48, HH), 256, 0, stream>>>(Wh1h, Wh2h, mph, mnh, rsph, rsnh, NND,
                                                    adj, flags, X1t, cc4,
                                                    (long)NND * 2 * DD, 2 * DD, DD);
    // wth block is [R=600][C=300] -> grid (10, 19)   [R2 bug: was swapped]
    for (int l = 0; l < HH; l++)
        k_transpose<<<dim3((DD + 31) / 32, (2 * DD + 31) / 32), tb, 0, stream>>>(
            wth, (size_t)l * 2 * DD * DD, wtT4 + (size_t)l * DD * 2 * DD, 2 * DD, DD, flags, 1);
    // head-batched concat GEMM with ELU -> x2 column blocks
    k_ccgemm<<<dim3(5, 48, HH), 256, 0, stream>>>(cc4, wtT4, x2, 2 * DD, DD, F2, 0, 0,
                                                  (long)NND * 2 * DD, (long)DD * 2 * DD, DD);
    // output layer
    k_transpose<<<dim3((F2 + 31) / 32, (NND + 31) / 32), tb, 0, stream>>>(x2, 0, X2t, NND, F2, flags, 0);
    k_uvec<<<dim3((F2 + 3) / 4, 1), 256, 0, stream>>>(Wo, ao, uo1, uo2, F2, DD, 0, 0, 0, flags);
    k_gemv2<<<dim3(NND / 4, 1), 256, 0, stream>>>(x2, uo1, uo2, Wh1o, Wh2o, NND, F2, 0, 0, flags, 0);
    k_stats<<<dim3(NND, 1), 256, 0, stream>>>(Wh1o, Wh2o, 0, adj, flags, mpo, mno, rspo, rsno);
    k_fattgemm<<<dim3(8, 48, 1), 256, 0, stream>>>(Wh1o, Wh2o, mpo, mno, rspo, rsno, 0,
                                                   adj, flags, X2t, ccO, 0, 2 * F2, F2);
    // wto is [R=2400][C=300] -> grid (10, 75)   [R2 bug: was swapped]
    k_transpose<<<dim3((DD + 31) / 32, (2 * F2 + 31) / 32), tb, 0, stream>>>(wto, 0, wtTo, 2 * F2, DD, flags, 1);
    k_ccgemm<<<dim3(5, 48, 1), 256, 0, stream>>>(ccO, wtTo, ofull, 2 * F2, DD, DD, 0, 1, 0, 0, 0);
    k_gather<<<(64 * DD + 255) / 256, 256, 0, stream>>>(ofull, tid, d_out, flags);
}